// Round 2
// baseline (305.918 us; speedup 1.0000x reference)
//
#include <hip/hip_runtime.h>
#include <hip/hip_bf16.h>

// Phase 0: init last_idx to -1 with a grid-stride int4 kernel (replaces the
// slow rocclr fillBufferAligned path for non-zero patterns).
__global__ void k_init_last(int4* __restrict__ last_idx4, int n4) {
    int stride = gridDim.x * blockDim.x;
    for (int i = blockIdx.x * blockDim.x + threadIdx.x; i < n4; i += stride) {
        last_idx4[i] = make_int4(-1, -1, -1, -1);
    }
}

// Phase 1: per-node last event index via atomicMax. 4 events per thread.
__global__ void k_last_idx(const int* __restrict__ node_ids,
                           int* __restrict__ last_idx, int E) {
    int base = (blockIdx.x * blockDim.x + threadIdx.x) * 4;
    if (base + 3 < E) {
        int4 nid = *reinterpret_cast<const int4*>(node_ids + base);
        atomicMax(&last_idx[nid.x], base + 0);
        atomicMax(&last_idx[nid.y], base + 1);
        atomicMax(&last_idx[nid.z], base + 2);
        atomicMax(&last_idx[nid.w], base + 3);
    } else {
        for (int i = base; i < E; ++i) {
            atomicMax(&last_idx[node_ids[i]], i);
        }
    }
}

// Phase 2 (fused): gather message rows + valid flag + times.
// 32 threads per node, one float4 (16B) each; row = 512B contiguous.
// Lane 0 of each group also writes valid and times.
__global__ void k_gather(const float4* __restrict__ msg,
                         const int* __restrict__ last_idx,
                         const float* __restrict__ times,
                         float4* __restrict__ out_msg,
                         float* __restrict__ out_valid,
                         float* __restrict__ out_times, int N) {
    int t = blockIdx.x * blockDim.x + threadIdx.x;
    int node = t >> 5;
    int q = t & 31;
    if (node >= N) return;
    int li = last_idx[node];
    float4 v = make_float4(0.f, 0.f, 0.f, 0.f);
    if (li >= 0) {
        v = msg[(size_t)li * 32 + q];
    }
    out_msg[(size_t)node * 32 + q] = v;
    if (q == 0) {
        out_valid[node] = (li >= 0) ? 1.0f : 0.0f;
        out_times[node] = (li >= 0) ? times[li] : 0.0f;
    }
}

extern "C" void kernel_launch(void* const* d_in, const int* in_sizes, int n_in,
                              void* d_out, int out_size, void* d_ws, size_t ws_size,
                              hipStream_t stream) {
    const int*   node_ids = (const int*)d_in[0];
    const float* msg      = (const float*)d_in[1];
    const float* times    = (const float*)d_in[2];
    // out = valid[N] + msg[N*128] + times[N] => out_size = 130*N
    const int E = in_sizes[0];
    const int N = out_size / 130;

    float* out_valid = (float*)d_out;
    float* out_msg   = (float*)d_out + N;
    float* out_times = (float*)d_out + N + (size_t)N * 128;

    int* last_idx = (int*)d_ws;  // N ints (4 MB)

    const int B = 256;

    // Phase 0: last_idx = -1 (N divisible by 4; guard anyway)
    int n4 = N / 4;
    k_init_last<<<2048, B, 0, stream>>>((int4*)last_idx, n4);

    // Phase 1: 4 events per thread
    int t1 = (E + 3) / 4;
    k_last_idx<<<(t1 + B - 1) / B, B, 0, stream>>>(node_ids, last_idx, E);

    // Phase 2: 32 threads per node, fused valid/times on lane 0
    long long total = (long long)N * 32;
    k_gather<<<(int)((total + B - 1) / B), B, 0, stream>>>(
        (const float4*)msg, last_idx, times,
        (float4*)out_msg, out_valid, out_times, N);
}

// Round 4
// 251.529 us; speedup vs baseline: 1.2162x; 1.2162x over previous
//
#include <hip/hip_runtime.h>
#include <hip/hip_bf16.h>

// Native vector type for nontemporal builtins (HIP's float4 is a class and
// is rejected by __builtin_nontemporal_load/store).
typedef float vf4 __attribute__((ext_vector_type(4)));

// Phase 0: init last_idx to -1 with a grid-stride int4 kernel.
__global__ void k_init_last(int4* __restrict__ last_idx4, int n4) {
    int stride = gridDim.x * blockDim.x;
    for (int i = blockIdx.x * blockDim.x + threadIdx.x; i < n4; i += stride) {
        last_idx4[i] = make_int4(-1, -1, -1, -1);
    }
}

// Phase 1: per-node last event index via atomicMax (1 event/thread).
__global__ void k_last_idx(const int* __restrict__ node_ids,
                           int* __restrict__ last_idx, int E) {
    int i = blockIdx.x * blockDim.x + threadIdx.x;
    if (i < E) {
        atomicMax(&last_idx[node_ids[i]], i);
    }
}

// Phase 2 (fused): gather message rows + valid flag + times.
// 8 threads per node, 4x16B each -> 4 outstanding loads per thread.
// Nontemporal on the single-touch msg/out streams.
__global__ void k_gather(const vf4* __restrict__ msg,
                         const int* __restrict__ last_idx,
                         const float* __restrict__ times,
                         vf4* __restrict__ out_msg,
                         float* __restrict__ out_valid,
                         float* __restrict__ out_times, int N) {
    int t = blockIdx.x * blockDim.x + threadIdx.x;
    int node = t >> 3;
    int q = t & 7;
    if (node >= N) return;
    int li = last_idx[node];
    size_t obase = (size_t)node * 32 + q;
    if (li >= 0) {
        size_t ibase = (size_t)li * 32 + q;
        vf4 v0 = __builtin_nontemporal_load(&msg[ibase]);
        vf4 v1 = __builtin_nontemporal_load(&msg[ibase + 8]);
        vf4 v2 = __builtin_nontemporal_load(&msg[ibase + 16]);
        vf4 v3 = __builtin_nontemporal_load(&msg[ibase + 24]);
        __builtin_nontemporal_store(v0, &out_msg[obase]);
        __builtin_nontemporal_store(v1, &out_msg[obase + 8]);
        __builtin_nontemporal_store(v2, &out_msg[obase + 16]);
        __builtin_nontemporal_store(v3, &out_msg[obase + 24]);
    } else {
        vf4 z = (vf4)0.0f;
        __builtin_nontemporal_store(z, &out_msg[obase]);
        __builtin_nontemporal_store(z, &out_msg[obase + 8]);
        __builtin_nontemporal_store(z, &out_msg[obase + 16]);
        __builtin_nontemporal_store(z, &out_msg[obase + 24]);
    }
    if (q == 0) {
        // times is 8 MB with ~2 touches/line on average -> keep cached.
        out_valid[node] = (li >= 0) ? 1.0f : 0.0f;
        out_times[node] = (li >= 0) ? times[li] : 0.0f;
    }
}

extern "C" void kernel_launch(void* const* d_in, const int* in_sizes, int n_in,
                              void* d_out, int out_size, void* d_ws, size_t ws_size,
                              hipStream_t stream) {
    const int*   node_ids = (const int*)d_in[0];
    const float* msg      = (const float*)d_in[1];
    const float* times    = (const float*)d_in[2];
    // out = valid[N] + msg[N*128] + times[N] => out_size = 130*N
    const int E = in_sizes[0];
    const int N = out_size / 130;

    float* out_valid = (float*)d_out;
    float* out_msg   = (float*)d_out + N;
    float* out_times = (float*)d_out + N + (size_t)N * 128;

    int* last_idx = (int*)d_ws;  // N ints (4 MB)

    const int B = 256;

    // Phase 0: last_idx = -1
    int n4 = N / 4;
    k_init_last<<<2048, B, 0, stream>>>((int4*)last_idx, n4);

    // Phase 1: 1 event per thread
    k_last_idx<<<(E + B - 1) / B, B, 0, stream>>>(node_ids, last_idx, E);

    // Phase 2: 8 threads per node, 64B each, fused valid/times on lane q==0
    long long total = (long long)N * 8;
    k_gather<<<(int)((total + B - 1) / B), B, 0, stream>>>(
        (const vf4*)msg, last_idx, times,
        (vf4*)out_msg, out_valid, out_times, N);
}